// Round 5
// baseline (537.434 us; speedup 1.0000x reference)
//
#include <hip/hip_runtime.h>
#include <math.h>

#define NB   32
#define C    8
#define D    4
#define H    256
#define W    256
#define HP   128
#define WP   128
#define MC   16
#define HO   126
#define WO   126
#define PATCH 144
#define OUTD 128
#define NL   (HO*WO)
#define HOG  6            // output rows per block (126 = 6*21)
#define NGRP (HO/HOG)     // 21
#define PROWS 9           // HOG+2 data rows + 1 zero row (for zero-pad tap 9)
#define BROW 168          // B row stride (bf16): 336 B, b128-aligned, bank-spread
#define NPOOLB 2048       // streaming pool blocks; block NPOOLB is the B-prep block

typedef float  f32x4  __attribute__((ext_vector_type(4)));
typedef __bf16 bf16x8 __attribute__((ext_vector_type(8)));

// ---------------------------------------------------------------------------
// Kernel 1: streaming LPPool3d(2,2,2,p=2) -> bf16 P[n][hp][wp][mc] in ws.
// Extra block (blockIdx==NPOOLB): reorder lin_w -> bf16 Bw[o][tap*16+mc] once.
// ---------------------------------------------------------------------------
__global__ __launch_bounds__(256, 4)
void pool_kernel(const float* __restrict__ x, const float* __restrict__ lin_w,
                 __bf16* __restrict__ Pg, __bf16* __restrict__ Bw) {
    int t = threadIdx.x;
    int b = blockIdx.x;

    if (b == NPOOLB) {   // ---- B-prep block ----
        int o = t & 127, kh = t >> 7;
#pragma unroll 4
        for (int kk = 0; kk < 80; kk++) {
            int kn = kh*80 + kk;
            int tap = kn >> 4, mc = kn & 15;
            float v = (tap < 9) ? lin_w[o*PATCH + mc*9 + tap] : 0.f;
            Bw[o*BROW + kn] = (__bf16)v;
        }
        return;
    }

    // thread -> (n, hp, wp pair, depth half); 64 consecutive wp2 -> dense loads
    int wp2 = t & 63;
    int dph = (t >> 6) & 1;
    int g = b*2 + (t >> 7);            // 4096 = 32 n * 128 hp
    int hp = g & 127, n = g >> 7;

    const float* xn = x + (size_t)n * (C*D*H*W) + (size_t)(2*dph) * (H*W)
                        + (2*hp)*W + 4*wp2;
    bf16x8 pk0, pk1;
#pragma unroll 2
    for (int c = 0; c < 8; c++) {
        const float* xb = xn + (size_t)c * (D*H*W);
        f32x4 a0 = *(const f32x4*)(xb);
        f32x4 a1 = *(const f32x4*)(xb + W);
        f32x4 a2 = *(const f32x4*)(xb + H*W);
        f32x4 a3 = *(const f32x4*)(xb + H*W + W);
        float s0 = a0.x*a0.x + a0.y*a0.y + a1.x*a1.x + a1.y*a1.y
                 + a2.x*a2.x + a2.y*a2.y + a3.x*a3.x + a3.y*a3.y;
        float s1 = a0.z*a0.z + a0.w*a0.w + a1.z*a1.z + a1.w*a1.w
                 + a2.z*a2.z + a2.w*a2.w + a3.z*a3.z + a3.w*a3.w;
        pk0[c] = (__bf16)sqrtf(s0);
        pk1[c] = (__bf16)sqrtf(s1);
    }
    __bf16* pr = Pg + ((size_t)n*HP + hp) * (WP*MC);
    *(bf16x8*)&pr[(2*wp2    )*16 + dph*8] = pk0;
    *(bf16x8*)&pr[(2*wp2 + 1)*16 + dph*8] = pk1;
}

// ---------------------------------------------------------------------------
// Kernel 2: im2col-free MFMA GEMM, 512 threads / 8 waves per block sharing the
// SAME 78 KB LDS tile: waves 0-3 -> hh 0-2, waves 4-7 -> hh 3-5, M-range by
// (wave&3). 2 blocks/CU x 8 waves = 4 waves/SIMD (was 2) -> latency hiding.
// Inner loop body identical to the verified r3 kernel (acc[2][8], no spill).
// ---------------------------------------------------------------------------
__global__ __launch_bounds__(512, 4)
void gemm_kernel(const __bf16* __restrict__ Pg, const __bf16* __restrict__ Bw,
                 const float* __restrict__ lin_b, float* __restrict__ accg) {
    __shared__ __align__(16) char smem[PROWS*128*32 + OUTD*BROW*2];   // 36864 + 43008 B
    __bf16* Pl   = (__bf16*)smem;                       // P[row][wp][mc], mc contiguous
    __bf16* Blds = (__bf16*)(smem + PROWS*128*32);      // B[o][k_new]

    int blk = blockIdx.x;
    int g = blk % NGRP, n = blk / NGRP;
    int ho0 = g * HOG;
    int t = threadIdx.x;
    int wave = t >> 6, lane = t & 63, quad = lane >> 4, l16 = lane & 15;
    int wr = wave & 3, h0 = (wave >> 2) * 3;

    // ---- stage P rows ho0..ho0+7 (32768 B) + zero row, and B (43008 B) ----
    {
        const f32x4* src = (const f32x4*)(Pg + ((size_t)n*HP + ho0) * (WP*MC));
        f32x4* dst = (f32x4*)Pl;
#pragma unroll
        for (int r = 0; r < 4; r++) dst[r*512 + t] = src[r*512 + t];
        f32x4 z = {};
        if (t < 256) dst[2048 + t] = z;               // zero row for tap 9
        const f32x4* bsrc = (const f32x4*)Bw;
        f32x4* bdst = (f32x4*)Blds;
#pragma unroll
        for (int r = 0; r < 5; r++) bdst[r*512 + t] = bsrc[r*512 + t];
        if (t < 128) bdst[2560 + t] = bsrc[2560 + t]; // 43008 B = 5.25 rounds
    }

    float lb[8];
#pragma unroll
    for (int nt = 0; nt < 8; nt++) lb[nt] = lin_b[nt*16 + l16];

    __syncthreads();

    float srun[8] = {0,0,0,0,0,0,0,0};
    int h8 = (quad & 1) * 8;
    int m0 = wr * 32 + l16;

    for (int hh = h0; hh < h0 + 3; hh++) {
        f32x4 acc[2][8] = {};
#pragma unroll
        for (int ks = 0; ks < 5; ks++) {
            int tap = 2*ks + (quad >> 1);        // per-lane, hoisted (ks unrolled)
            int it = (tap * 11) >> 5;            // tap/3 for tap<10
            int jt = tap - it * 3;               // tap%3
            bf16x8 afr[2];
#pragma unroll
            for (int mt = 0; mt < 2; mt++) {
                int m = m0 + mt*16;
                afr[mt] = *(const bf16x8*)&Pl[((hh + it)*128 + m + jt)*16 + h8];
            }
#pragma unroll
            for (int nt = 0; nt < 8; nt++) {
                bf16x8 bfr = *(const bf16x8*)&Blds[(nt*16 + l16)*BROW + ks*32 + quad*8];
                acc[0][nt] = __builtin_amdgcn_mfma_f32_16x16x32_bf16(afr[0], bfr, acc[0][nt], 0, 0, 0);
                acc[1][nt] = __builtin_amdgcn_mfma_f32_16x16x32_bf16(afr[1], bfr, acc[1][nt], 0, 0, 0);
            }
        }
        // epilogue: bias + CELU + mask + reduce over patch rows
#pragma unroll
        for (int nt = 0; nt < 8; nt++) {
            float s = 0.f;
#pragma unroll
            for (int mt = 0; mt < 2; mt++) {
                int mb = wr*32 + mt*16 + quad*4;
#pragma unroll
                for (int r = 0; r < 4; r++) {
                    float p = acc[mt][nt][r] + lb[nt];
                    float a = (p > 0.f) ? p : (__expf(p) - 1.f);
                    if (mb + r < WO) s += a;
                }
            }
            s += __shfl_xor(s, 16, 64);
            s += __shfl_xor(s, 32, 64);
            srun[nt] += s;
        }
    }

    __syncthreads();                       // all P/B reads done; alias red over P
    float* red = (float*)smem;
    if (quad == 0) {
#pragma unroll
        for (int nt = 0; nt < 8; nt++) red[wave*OUTD + nt*16 + l16] = srun[nt];
    }
    __syncthreads();
    if (t < OUTD) {
        float tot = 0.f;
#pragma unroll
        for (int w = 0; w < 8; w++) tot += red[w*OUTD + t];
        atomicAdd(&accg[n*OUTD + t], tot);
    }
}

// ---------------------------------------------------------------------------
// Fallback path: the harness-verified round-0 fused kernel, verbatim.
// Used when ws_size cannot hold the P + B intermediates.
// ---------------------------------------------------------------------------
__global__ __launch_bounds__(256, 2)
void fused_kernel(const float* __restrict__ x, const float* __restrict__ lin_w,
                  const float* __restrict__ lin_b, float* __restrict__ accg) {
    __shared__ __align__(16) char smem[PROWS*128*32 + OUTD*BROW*2];
    __bf16* Pl   = (__bf16*)smem;
    __bf16* Blds = (__bf16*)(smem + PROWS*128*32);

    int blk = blockIdx.x;
    int g = blk % NGRP, n = blk / NGRP;
    int ho0 = g * HOG;
    int t = threadIdx.x;
    int wave = t >> 6, lane = t & 63, quad = lane >> 4, l16 = lane & 15;

    {
        int wp = t & 127, dph = t >> 7;
        const float* xn = x + (size_t)n * (C*D*H*W);
#pragma unroll 2
        for (int i = 0; i < 8; i++) {
            int hp = ho0 + i;
            bf16x8 pk;
#pragma unroll
            for (int c = 0; c < 8; c++) {
                const float* xb = xn + ((c*4 + 2*dph) * H + 2*hp) * W + 2*wp;
                float2 a0 = *(const float2*)(xb);
                float2 a1 = *(const float2*)(xb + W);
                float2 a2 = *(const float2*)(xb + H*W);
                float2 a3 = *(const float2*)(xb + H*W + W);
                float s = a0.x*a0.x + a0.y*a0.y + a1.x*a1.x + a1.y*a1.y
                        + a2.x*a2.x + a2.y*a2.y + a3.x*a3.x + a3.y*a3.y;
                pk[c] = (__bf16)sqrtf(s);
            }
            *(bf16x8*)&Pl[(i*128 + wp)*16 + dph*8] = pk;
        }
        bf16x8 z = {};
        *(bf16x8*)&Pl[(8*128 + wp)*16 + dph*8] = z;
    }
    {
        int o = t & 127, kh = t >> 7;
#pragma unroll 4
        for (int kk = 0; kk < 80; kk++) {
            int kn = kh*80 + kk;
            int tap = kn >> 4, mc = kn & 15;
            float v = (tap < 9) ? lin_w[o*PATCH + mc*9 + tap] : 0.f;
            Blds[o*BROW + kn] = (__bf16)v;
        }
    }

    float lb[8];
#pragma unroll
    for (int nt = 0; nt < 8; nt++) lb[nt] = lin_b[nt*16 + l16];

    __syncthreads();

    float srun[8] = {0,0,0,0,0,0,0,0};
    int h8 = (quad & 1) * 8;
    int m0 = wave * 32 + l16;

    for (int hh = 0; hh < HOG; hh++) {
        f32x4 acc[2][8] = {};
#pragma unroll
        for (int ks = 0; ks < 5; ks++) {
            int tap = 2*ks + (quad >> 1);
            int it = (tap * 11) >> 5;
            int jt = tap - it * 3;
            bf16x8 afr[2];
#pragma unroll
            for (int mt = 0; mt < 2; mt++) {
                int m = m0 + mt*16;
                afr[mt] = *(const bf16x8*)&Pl[((hh + it)*128 + m + jt)*16 + h8];
            }
#pragma unroll
            for (int nt = 0; nt < 8; nt++) {
                bf16x8 bfr = *(const bf16x8*)&Blds[(nt*16 + l16)*BROW + ks*32 + quad*8];
                acc[0][nt] = __builtin_amdgcn_mfma_f32_16x16x32_bf16(afr[0], bfr, acc[0][nt], 0, 0, 0);
                acc[1][nt] = __builtin_amdgcn_mfma_f32_16x16x32_bf16(afr[1], bfr, acc[1][nt], 0, 0, 0);
            }
        }
#pragma unroll
        for (int nt = 0; nt < 8; nt++) {
            float s = 0.f;
#pragma unroll
            for (int mt = 0; mt < 2; mt++) {
                int mb = wave*32 + mt*16 + quad*4;
#pragma unroll
                for (int r = 0; r < 4; r++) {
                    float p = acc[mt][nt][r] + lb[nt];
                    float a = (p > 0.f) ? p : (__expf(p) - 1.f);
                    if (mb + r < WO) s += a;
                }
            }
            s += __shfl_xor(s, 16, 64);
            s += __shfl_xor(s, 32, 64);
            srun[nt] += s;
        }
    }

    __syncthreads();
    float* red = (float*)smem;
    if (quad == 0) {
#pragma unroll
        for (int nt = 0; nt < 8; nt++) red[wave*OUTD + nt*16 + l16] = srun[nt];
    }
    __syncthreads();
    if (t < OUTD) {
        float tot = red[t] + red[OUTD+t] + red[2*OUTD+t] + red[3*OUTD+t];
        atomicAdd(&accg[n*OUTD + t], tot);
    }
}

// ---------------- mean + clamped L2 normalize ------------------------------
__global__ void finalize_kernel(const float* __restrict__ acc, float* __restrict__ out) {
    int n = blockIdx.x;
    int o = threadIdx.x;     // 128 threads
    float a = acc[n * OUTD + o] * (1.0f / (float)NL);
    float s = a * a;
#pragma unroll
    for (int off = 32; off > 0; off >>= 1) s += __shfl_down(s, off, 64);
    __shared__ float partial[2];
    if ((o & 63) == 0) partial[o >> 6] = s;
    __syncthreads();
    float norm = sqrtf(partial[0] + partial[1]);
    norm = fmaxf(norm, 1e-6f);
    out[n * OUTD + o] = a / norm;
}

extern "C" void kernel_launch(void* const* d_in, const int* in_sizes, int n_in,
                              void* d_out, int out_size, void* d_ws, size_t ws_size,
                              hipStream_t stream) {
    const float* x     = (const float*)d_in[0];
    const float* lin_w = (const float*)d_in[1];
    const float* lin_b = (const float*)d_in[2];
    float* out = (float*)d_out;

    float* acc = (float*)d_ws;   // 32*128 floats = 16 KB
    hipMemsetAsync(acc, 0, NB * OUTD * sizeof(float), stream);

    const size_t BW_BYTES = (size_t)OUTD * BROW * sizeof(__bf16);        // 43008
    const size_t PG_BYTES = (size_t)NB * HP * WP * MC * sizeof(__bf16);  // 16.78 MB
    if (ws_size >= 16384 + BW_BYTES + PG_BYTES) {
        __bf16* Bw = (__bf16*)((char*)d_ws + 16384);
        __bf16* Pg = (__bf16*)((char*)d_ws + 16384 + BW_BYTES);
        pool_kernel<<<NPOOLB + 1, 256, 0, stream>>>(x, lin_w, Pg, Bw);
        gemm_kernel<<<NB * NGRP, 512, 0, stream>>>(Pg, Bw, lin_b, acc);
    } else {
        fused_kernel<<<NB * NGRP, 256, 0, stream>>>(x, lin_w, lin_b, acc);
    }
    finalize_kernel<<<NB, OUTD, 0, stream>>>(acc, out);
}

// Round 6
// 426.720 us; speedup vs baseline: 1.2595x; 1.2595x over previous
//
#include <hip/hip_runtime.h>
#include <math.h>

#define NB   32
#define C    8
#define D    4
#define H    256
#define W    256
#define HP   128
#define WP   128
#define MC   16
#define HO   126
#define WO   126
#define PATCH 144
#define OUTD 128
#define NL   (HO*WO)
#define HOG  6            // output rows per block (126 = 6*21)
#define NGRP (HO/HOG)     // 21
#define PROWS 9           // HOG+2 data rows + 1 zero row (for zero-pad tap 9)
#define BROW 168          // B row stride (bf16): 336 B, b128-aligned, bank-spread
#define NPOOLB 2048       // streaming pool blocks; block NPOOLB is the B-prep block

typedef float  f32x4  __attribute__((ext_vector_type(4)));
typedef __bf16 bf16x8 __attribute__((ext_vector_type(8)));

// ---------------------------------------------------------------------------
// Kernel 1: streaming LPPool3d(2,2,2,p=2) -> bf16 P[n][hp][wp][mc] in ws.
// Extra block (blockIdx==NPOOLB): reorder lin_w -> bf16 Bw[o][tap*16+mc] once.
// ---------------------------------------------------------------------------
__global__ __launch_bounds__(256, 4)
void pool_kernel(const float* __restrict__ x, const float* __restrict__ lin_w,
                 __bf16* __restrict__ Pg, __bf16* __restrict__ Bw) {
    int t = threadIdx.x;
    int b = blockIdx.x;

    if (b == NPOOLB) {   // ---- B-prep block ----
        int o = t & 127, kh = t >> 7;
#pragma unroll 4
        for (int kk = 0; kk < 80; kk++) {
            int kn = kh*80 + kk;
            int tap = kn >> 4, mc = kn & 15;
            float v = (tap < 9) ? lin_w[o*PATCH + mc*9 + tap] : 0.f;
            Bw[o*BROW + kn] = (__bf16)v;
        }
        return;
    }

    // thread -> (n, hp, wp pair, depth half); 64 consecutive wp2 -> dense loads
    int wp2 = t & 63;
    int dph = (t >> 6) & 1;
    int g = b*2 + (t >> 7);            // 4096 = 32 n * 128 hp
    int hp = g & 127, n = g >> 7;

    const float* xn = x + (size_t)n * (C*D*H*W) + (size_t)(2*dph) * (H*W)
                        + (2*hp)*W + 4*wp2;
    bf16x8 pk0, pk1;
#pragma unroll 2
    for (int c = 0; c < 8; c++) {
        const float* xb = xn + (size_t)c * (D*H*W);
        f32x4 a0 = *(const f32x4*)(xb);
        f32x4 a1 = *(const f32x4*)(xb + W);
        f32x4 a2 = *(const f32x4*)(xb + H*W);
        f32x4 a3 = *(const f32x4*)(xb + H*W + W);
        float s0 = a0.x*a0.x + a0.y*a0.y + a1.x*a1.x + a1.y*a1.y
                 + a2.x*a2.x + a2.y*a2.y + a3.x*a3.x + a3.y*a3.y;
        float s1 = a0.z*a0.z + a0.w*a0.w + a1.z*a1.z + a1.w*a1.w
                 + a2.z*a2.z + a2.w*a2.w + a3.z*a3.z + a3.w*a3.w;
        pk0[c] = (__bf16)sqrtf(s0);
        pk1[c] = (__bf16)sqrtf(s1);
    }
    __bf16* pr = Pg + ((size_t)n*HP + hp) * (WP*MC);
    *(bf16x8*)&pr[(2*wp2    )*16 + dph*8] = pk0;
    *(bf16x8*)&pr[(2*wp2 + 1)*16 + dph*8] = pk1;
}

// ---------------------------------------------------------------------------
// Kernel 2: im2col-free MFMA GEMM, 512 threads / 8 waves per block sharing the
// SAME 78 KB LDS tile: waves 0-3 -> hh 0-2, waves 4-7 -> hh 3-5, M-range by
// (wave&3). LAUNCH_BOUNDS (512,2): r5's (512,4) capped VGPR at 64 -> acc[2][8]
// (64 regs) spilled every access (FETCH 345MB, WRITE 269MB scratch traffic).
// (512,2) restores the 128-VGPR budget this body verified-compiles into.
// ---------------------------------------------------------------------------
__global__ __launch_bounds__(512, 2)
void gemm_kernel(const __bf16* __restrict__ Pg, const __bf16* __restrict__ Bw,
                 const float* __restrict__ lin_b, float* __restrict__ accg) {
    __shared__ __align__(16) char smem[PROWS*128*32 + OUTD*BROW*2];   // 36864 + 43008 B
    __bf16* Pl   = (__bf16*)smem;                       // P[row][wp][mc], mc contiguous
    __bf16* Blds = (__bf16*)(smem + PROWS*128*32);      // B[o][k_new]

    int blk = blockIdx.x;
    int g = blk % NGRP, n = blk / NGRP;
    int ho0 = g * HOG;
    int t = threadIdx.x;
    int wave = t >> 6, lane = t & 63, quad = lane >> 4, l16 = lane & 15;
    int wr = wave & 3, h0 = (wave >> 2) * 3;

    // ---- stage P rows ho0..ho0+7 (32768 B) + zero row, and B (43008 B) ----
    {
        const f32x4* src = (const f32x4*)(Pg + ((size_t)n*HP + ho0) * (WP*MC));
        f32x4* dst = (f32x4*)Pl;
#pragma unroll
        for (int r = 0; r < 4; r++) dst[r*512 + t] = src[r*512 + t];
        f32x4 z = {};
        if (t < 256) dst[2048 + t] = z;               // zero row for tap 9
        const f32x4* bsrc = (const f32x4*)Bw;
        f32x4* bdst = (f32x4*)Blds;
#pragma unroll
        for (int r = 0; r < 5; r++) bdst[r*512 + t] = bsrc[r*512 + t];
        if (t < 128) bdst[2560 + t] = bsrc[2560 + t]; // 43008 B = 5.25 rounds
    }

    float lb[8];
#pragma unroll
    for (int nt = 0; nt < 8; nt++) lb[nt] = lin_b[nt*16 + l16];

    __syncthreads();

    float srun[8] = {0,0,0,0,0,0,0,0};
    int h8 = (quad & 1) * 8;
    int m0 = wr * 32 + l16;

    for (int hh = h0; hh < h0 + 3; hh++) {
        f32x4 acc[2][8] = {};
#pragma unroll
        for (int ks = 0; ks < 5; ks++) {
            int tap = 2*ks + (quad >> 1);        // per-lane, hoisted (ks unrolled)
            int it = (tap * 11) >> 5;            // tap/3 for tap<10
            int jt = tap - it * 3;               // tap%3
            bf16x8 afr[2];
#pragma unroll
            for (int mt = 0; mt < 2; mt++) {
                int m = m0 + mt*16;
                afr[mt] = *(const bf16x8*)&Pl[((hh + it)*128 + m + jt)*16 + h8];
            }
#pragma unroll
            for (int nt = 0; nt < 8; nt++) {
                bf16x8 bfr = *(const bf16x8*)&Blds[(nt*16 + l16)*BROW + ks*32 + quad*8];
                acc[0][nt] = __builtin_amdgcn_mfma_f32_16x16x32_bf16(afr[0], bfr, acc[0][nt], 0, 0, 0);
                acc[1][nt] = __builtin_amdgcn_mfma_f32_16x16x32_bf16(afr[1], bfr, acc[1][nt], 0, 0, 0);
            }
        }
        // epilogue: bias + CELU + mask + reduce over patch rows
#pragma unroll
        for (int nt = 0; nt < 8; nt++) {
            float s = 0.f;
#pragma unroll
            for (int mt = 0; mt < 2; mt++) {
                int mb = wr*32 + mt*16 + quad*4;
#pragma unroll
                for (int r = 0; r < 4; r++) {
                    float p = acc[mt][nt][r] + lb[nt];
                    float a = (p > 0.f) ? p : (__expf(p) - 1.f);
                    if (mb + r < WO) s += a;
                }
            }
            s += __shfl_xor(s, 16, 64);
            s += __shfl_xor(s, 32, 64);
            srun[nt] += s;
        }
    }

    __syncthreads();                       // all P/B reads done; alias red over P
    float* red = (float*)smem;
    if (quad == 0) {
#pragma unroll
        for (int nt = 0; nt < 8; nt++) red[wave*OUTD + nt*16 + l16] = srun[nt];
    }
    __syncthreads();
    if (t < OUTD) {
        float tot = 0.f;
#pragma unroll
        for (int w = 0; w < 8; w++) tot += red[w*OUTD + t];
        atomicAdd(&accg[n*OUTD + t], tot);
    }
}

// ---------------------------------------------------------------------------
// Fallback path: the harness-verified round-0 fused kernel, verbatim.
// Used when ws_size cannot hold the P + B intermediates.
// ---------------------------------------------------------------------------
__global__ __launch_bounds__(256, 2)
void fused_kernel(const float* __restrict__ x, const float* __restrict__ lin_w,
                  const float* __restrict__ lin_b, float* __restrict__ accg) {
    __shared__ __align__(16) char smem[PROWS*128*32 + OUTD*BROW*2];
    __bf16* Pl   = (__bf16*)smem;
    __bf16* Blds = (__bf16*)(smem + PROWS*128*32);

    int blk = blockIdx.x;
    int g = blk % NGRP, n = blk / NGRP;
    int ho0 = g * HOG;
    int t = threadIdx.x;
    int wave = t >> 6, lane = t & 63, quad = lane >> 4, l16 = lane & 15;

    {
        int wp = t & 127, dph = t >> 7;
        const float* xn = x + (size_t)n * (C*D*H*W);
#pragma unroll 2
        for (int i = 0; i < 8; i++) {
            int hp = ho0 + i;
            bf16x8 pk;
#pragma unroll
            for (int c = 0; c < 8; c++) {
                const float* xb = xn + ((c*4 + 2*dph) * H + 2*hp) * W + 2*wp;
                float2 a0 = *(const float2*)(xb);
                float2 a1 = *(const float2*)(xb + W);
                float2 a2 = *(const float2*)(xb + H*W);
                float2 a3 = *(const float2*)(xb + H*W + W);
                float s = a0.x*a0.x + a0.y*a0.y + a1.x*a1.x + a1.y*a1.y
                        + a2.x*a2.x + a2.y*a2.y + a3.x*a3.x + a3.y*a3.y;
                pk[c] = (__bf16)sqrtf(s);
            }
            *(bf16x8*)&Pl[(i*128 + wp)*16 + dph*8] = pk;
        }
        bf16x8 z = {};
        *(bf16x8*)&Pl[(8*128 + wp)*16 + dph*8] = z;
    }
    {
        int o = t & 127, kh = t >> 7;
#pragma unroll 4
        for (int kk = 0; kk < 80; kk++) {
            int kn = kh*80 + kk;
            int tap = kn >> 4, mc = kn & 15;
            float v = (tap < 9) ? lin_w[o*PATCH + mc*9 + tap] : 0.f;
            Blds[o*BROW + kn] = (__bf16)v;
        }
    }

    float lb[8];
#pragma unroll
    for (int nt = 0; nt < 8; nt++) lb[nt] = lin_b[nt*16 + l16];

    __syncthreads();

    float srun[8] = {0,0,0,0,0,0,0,0};
    int h8 = (quad & 1) * 8;
    int m0 = wave * 32 + l16;

    for (int hh = 0; hh < HOG; hh++) {
        f32x4 acc[2][8] = {};
#pragma unroll
        for (int ks = 0; ks < 5; ks++) {
            int tap = 2*ks + (quad >> 1);
            int it = (tap * 11) >> 5;
            int jt = tap - it * 3;
            bf16x8 afr[2];
#pragma unroll
            for (int mt = 0; mt < 2; mt++) {
                int m = m0 + mt*16;
                afr[mt] = *(const bf16x8*)&Pl[((hh + it)*128 + m + jt)*16 + h8];
            }
#pragma unroll
            for (int nt = 0; nt < 8; nt++) {
                bf16x8 bfr = *(const bf16x8*)&Blds[(nt*16 + l16)*BROW + ks*32 + quad*8];
                acc[0][nt] = __builtin_amdgcn_mfma_f32_16x16x32_bf16(afr[0], bfr, acc[0][nt], 0, 0, 0);
                acc[1][nt] = __builtin_amdgcn_mfma_f32_16x16x32_bf16(afr[1], bfr, acc[1][nt], 0, 0, 0);
            }
        }
#pragma unroll
        for (int nt = 0; nt < 8; nt++) {
            float s = 0.f;
#pragma unroll
            for (int mt = 0; mt < 2; mt++) {
                int mb = wave*32 + mt*16 + quad*4;
#pragma unroll
                for (int r = 0; r < 4; r++) {
                    float p = acc[mt][nt][r] + lb[nt];
                    float a = (p > 0.f) ? p : (__expf(p) - 1.f);
                    if (mb + r < WO) s += a;
                }
            }
            s += __shfl_xor(s, 16, 64);
            s += __shfl_xor(s, 32, 64);
            srun[nt] += s;
        }
    }

    __syncthreads();
    float* red = (float*)smem;
    if (quad == 0) {
#pragma unroll
        for (int nt = 0; nt < 8; nt++) red[wave*OUTD + nt*16 + l16] = srun[nt];
    }
    __syncthreads();
    if (t < OUTD) {
        float tot = red[t] + red[OUTD+t] + red[2*OUTD+t] + red[3*OUTD+t];
        atomicAdd(&accg[n*OUTD + t], tot);
    }
}

// ---------------- mean + clamped L2 normalize ------------------------------
__global__ void finalize_kernel(const float* __restrict__ acc, float* __restrict__ out) {
    int n = blockIdx.x;
    int o = threadIdx.x;     // 128 threads
    float a = acc[n * OUTD + o] * (1.0f / (float)NL);
    float s = a * a;
#pragma unroll
    for (int off = 32; off > 0; off >>= 1) s += __shfl_down(s, off, 64);
    __shared__ float partial[2];
    if ((o & 63) == 0) partial[o >> 6] = s;
    __syncthreads();
    float norm = sqrtf(partial[0] + partial[1]);
    norm = fmaxf(norm, 1e-6f);
    out[n * OUTD + o] = a / norm;
}

extern "C" void kernel_launch(void* const* d_in, const int* in_sizes, int n_in,
                              void* d_out, int out_size, void* d_ws, size_t ws_size,
                              hipStream_t stream) {
    const float* x     = (const float*)d_in[0];
    const float* lin_w = (const float*)d_in[1];
    const float* lin_b = (const float*)d_in[2];
    float* out = (float*)d_out;

    float* acc = (float*)d_ws;   // 32*128 floats = 16 KB
    hipMemsetAsync(acc, 0, NB * OUTD * sizeof(float), stream);

    const size_t BW_BYTES = (size_t)OUTD * BROW * sizeof(__bf16);        // 43008
    const size_t PG_BYTES = (size_t)NB * HP * WP * MC * sizeof(__bf16);  // 16.78 MB
    if (ws_size >= 16384 + BW_BYTES + PG_BYTES) {
        __bf16* Bw = (__bf16*)((char*)d_ws + 16384);
        __bf16* Pg = (__bf16*)((char*)d_ws + 16384 + BW_BYTES);
        pool_kernel<<<NPOOLB + 1, 256, 0, stream>>>(x, lin_w, Pg, Bw);
        gemm_kernel<<<NB * NGRP, 512, 0, stream>>>(Pg, Bw, lin_b, acc);
    } else {
        fused_kernel<<<NB * NGRP, 256, 0, stream>>>(x, lin_w, lin_b, acc);
    }
    finalize_kernel<<<NB, OUTD, 0, stream>>>(acc, out);
}